// Round 2
// 125.672 us; speedup vs baseline: 1.0165x; 1.0165x over previous
//
#include <hip/hip_runtime.h>
#include <hip/hip_bf16.h>

#define IN_FT 512
#define OUT_FT 128
#define NEG_SLOPE 0.2f
#define SHIFT_C 4.0f    // global score shift: softmax-invariant, guards exp overflow
#define CAP8 768        // per-bin capacity: 8 dsts, mean 512 edges, +11 sigma
#define NBMAX 1280

typedef __attribute__((ext_vector_type(8))) short short8;
typedef __attribute__((ext_vector_type(4))) short short4v;
typedef __attribute__((ext_vector_type(4))) float float4v;

__device__ inline short f2bf_s(float x) {
    __hip_bfloat16 b = __float2bfloat16(x);
    union { __hip_bfloat16 b; short s; } u;
    u.b = b;
    return u.s;
}
__device__ inline float bf2f(short s) {
    union { float f; unsigned u; } u;
    u.u = ((unsigned)(unsigned short)s) << 16;
    return u.f;
}

// ---------------- K1: W_comb = W_gat @ W_fc -> bf16 in MFMA B-fragment order
// (blocks 0..255); blocks >=256 zero the bin cursors. ----------------
__global__ void k_prep(const float* __restrict__ Wg,
                       const float* __restrict__ Wf,
                       short* __restrict__ whf,
                       int* __restrict__ gcur, int nb) {
    if (blockIdx.x >= 256) {
        int i = (blockIdx.x - 256) * 256 + threadIdx.x;
        if (i < nb) gcur[i] = 0;
        return;
    }
    int idx = blockIdx.x * blockDim.x + threadIdx.x;  // 0..65535
    int o = idx >> 9;
    int k = idx & 511;
    float s = 0.f;
    // unroll 16: 1 wave/SIMD here, so MLP (outstanding loads) is the only
    // latency hiding — 8 batches of 16 instead of 16 batches of 8.
#pragma unroll 16
    for (int j = 0; j < OUT_FT; ++j)
        s += Wg[o * OUT_FT + j] * Wf[j * IN_FT + k];
    int t = o >> 4, l15 = o & 15;
    int kc = k >> 5, q = (k >> 3) & 3, jj = k & 7;
    whf[(((kc * 8 + t) * 64) + q * 16 + l15) * 8 + jj] = f2bf_s(s);
}

// ---------------- K2: [0..GB) gemm (LDS-staged A, 32 rows/block, NO split-K:
// wave w owns column tiles {2w,2w+1} over full K) + att logits;
// [GB..) phase-1 coarse binning of edges (bin = dst>>3). ----
__launch_bounds__(256)
__global__ void k_main(const float* __restrict__ seq,
                       const short8* __restrict__ whf,
                       const float* __restrict__ att_s_v,
                       const float* __restrict__ att_d_v,
                       short* __restrict__ h16,
                       float* __restrict__ a_s,
                       float* __restrict__ a_d,
                       const int* __restrict__ src,
                       const int* __restrict__ dstv,
                       int* __restrict__ gcur,
                       unsigned* __restrict__ bins,
                       int N, int E, int nb, int GB) {
    __shared__ char smem[33792];   // 32 KB A-tile (2 x 8192 shorts) + 1 KB logit partials
    if (blockIdx.x >= GB) {
        // ---- phase-1 binning: this block owns 2048 consecutive edges ----
        int* hist  = (int*)smem;          // [NBMAX]
        int* sbase = hist + NBMAX;        // [NBMAX]
        int* scur  = sbase + NBMAX;       // 3*1280*4 = 15.4 KB
        int e0 = (blockIdx.x - GB) * 2048;
        for (int t = threadIdx.x; t < nb; t += 256) hist[t] = 0;
        __syncthreads();
        int myd[8];
#pragma unroll
        for (int k = 0; k < 8; ++k) {
            int e = e0 + k * 256 + threadIdx.x;
            myd[k] = (e < E) ? dstv[e] : -1;
            if ((unsigned)myd[k] < (unsigned)N) atomicAdd(&hist[myd[k] >> 3], 1);
            else myd[k] = -1;
        }
        __syncthreads();
        for (int t = threadIdx.x; t < nb; t += 256) {
            int c = hist[t];
            sbase[t] = c ? atomicAdd(&gcur[t], c) : 0;
            scur[t] = 0;
        }
        __syncthreads();
#pragma unroll
        for (int k = 0; k < 8; ++k) {
            if (myd[k] >= 0) {
                int e = e0 + k * 256 + threadIdx.x;
                int b = myd[k] >> 3;
                int slot = sbase[b] + atomicAdd(&scur[b], 1);
                if (slot < CAP8) {
                    int s = src[e];
                    if ((unsigned)s >= (unsigned)N) s = 0;
                    bins[(size_t)b * CAP8 + slot] = ((unsigned)s << 3) | (myd[k] & 7);
                }
            }
        }
        return;
    }
    // ---- gemm: tile 32 rows x 128 cols. Wave w owns col tiles {2w,2w+1};
    //      loops full K (16 kc steps), accumulating 4 fragments — no split-K
    //      reduction, no idle-wave epilogue. ----
    short* As = (short*)smem;              // [rg][kc][q][r16][8] shorts; rg stride 8192 SHORTS

    int wave = threadIdx.x >> 6;
    int lane = threadIdx.x & 63;
    int l15 = lane & 15, quad = lane >> 4;
    int rows0 = blockIdx.x * 32;

#pragma unroll
    for (int i = 0; i < 16; ++i) {
        int idx = threadIdx.x + 256 * i;   // 0..4095 float4s
        int r = idx >> 7, c4 = idx & 127;  // r 0..31
        int row = rows0 + r;
        int rowc = row < N ? row : N - 1;
        float4 v = *(const float4*)(seq + (size_t)rowc * IN_FT + c4 * 4);
        short4v b;
        b[0] = f2bf_s(v.x); b[1] = f2bf_s(v.y); b[2] = f2bf_s(v.z); b[3] = f2bf_s(v.w);
        int rg = r >> 4, r16 = r & 15;
        int kc = c4 >> 3, q = (c4 >> 1) & 3, half = c4 & 1;
        *(short4v*)(As + rg * 8192 + ((kc * 4 + q) * 16 + r16) * 8 + half * 4) = b;
    }
    __syncthreads();

    float4v accs[2][2];
#pragma unroll
    for (int rg = 0; rg < 2; ++rg)
#pragma unroll
        for (int tt = 0; tt < 2; ++tt) accs[rg][tt] = (float4v){0.f, 0.f, 0.f, 0.f};

    const short8* wp = whf + lane;
#pragma unroll
    for (int kc = 0; kc < 16; ++kc) {
        short8 a0 = *(const short8*)(As + ((kc * 4 + quad) * 16 + l15) * 8);
        short8 a1 = *(const short8*)(As + 8192 + ((kc * 4 + quad) * 16 + l15) * 8);
        short8 b0 = wp[(size_t)(kc * 8 + 2 * wave) * 64];
        short8 b1 = wp[(size_t)(kc * 8 + 2 * wave + 1) * 64];
        accs[0][0] = __builtin_amdgcn_mfma_f32_16x16x32_bf16(a0, b0, accs[0][0], 0, 0, 0);
        accs[0][1] = __builtin_amdgcn_mfma_f32_16x16x32_bf16(a0, b1, accs[0][1], 0, 0, 0);
        accs[1][0] = __builtin_amdgcn_mfma_f32_16x16x32_bf16(a1, b0, accs[1][0], 0, 0, 0);
        accs[1][1] = __builtin_amdgcn_mfma_f32_16x16x32_bf16(a1, b1, accs[1][1], 0, 0, 0);
    }

    // epilogue (all 4 waves): h16 stores for this wave's 2 column tiles
#pragma unroll
    for (int rg = 0; rg < 2; ++rg)
#pragma unroll
        for (int tt = 0; tt < 2; ++tt) {
            int t = 2 * wave + tt;
#pragma unroll
            for (int r = 0; r < 4; ++r) {
                int rr = rows0 + rg * 16 + quad * 4 + r;
                if (rr < N)
                    h16[(size_t)rr * OUT_FT + t * 16 + l15] = f2bf_s(accs[rg][tt][r]);
            }
        }

    // logits: per-wave partial dot over its 32 features, then cross-wave sum
    float asv0 = att_s_v[(2 * wave) * 16 + l15];
    float asv1 = att_s_v[(2 * wave + 1) * 16 + l15];
    float adv0 = att_d_v[(2 * wave) * 16 + l15];
    float adv1 = att_d_v[(2 * wave + 1) * 16 + l15];
    float* psh = (float*)(smem + 32768);   // [4][32]
    float* pdh = psh + 128;                // [4][32]
#pragma unroll
    for (int rg = 0; rg < 2; ++rg)
#pragma unroll
        for (int r = 0; r < 4; ++r) {
            float ps = accs[rg][0][r] * asv0 + accs[rg][1][r] * asv1;
            float pd = accs[rg][0][r] * adv0 + accs[rg][1][r] * adv1;
#pragma unroll
            for (int m = 1; m < 16; m <<= 1) {
                ps += __shfl_xor(ps, m);
                pd += __shfl_xor(pd, m);
            }
            if (l15 == 0) {
                int row = rg * 16 + quad * 4 + r;
                psh[wave * 32 + row] = ps;
                pdh[wave * 32 + row] = pd;
            }
        }
    __syncthreads();
    if (threadIdx.x < 32) {
        int rr = rows0 + threadIdx.x;
        if (rr < N) {
            float s = psh[threadIdx.x] + psh[32 + threadIdx.x] +
                      psh[64 + threadIdx.x] + psh[96 + threadIdx.x];
            float d = pdh[threadIdx.x] + pdh[32 + threadIdx.x] +
                      pdh[64 + threadIdx.x] + pdh[96 + threadIdx.x];
            a_s[rr] = s; a_d[rr] = d;
        }
    }
}

// ---------------- K3: one block per bin (8 dsts). In-LDS counting sort into
// 8-padded (src, p) segments (sentinels p=0), then wave-per-dst-PAIR register
// accumulation: two dsts interleaved -> 16 gathers in flight, guard-free. ----
__launch_bounds__(256)
__global__ void k_agg(const short* __restrict__ h16, const float* __restrict__ a_s,
                      const float* __restrict__ a_d,
                      const int* __restrict__ gcur, const unsigned* __restrict__ bins,
                      const float* __restrict__ gat_bias,
                      const float* __restrict__ bias,
                      const float* __restrict__ prelu_a,
                      float* __restrict__ out, int N) {
    __shared__ int2  spair[CAP8 + 64];
    __shared__ int   hist[8], base[8], cur8[8];
    __shared__ float ads[8];
    int b = blockIdx.x;
    int d0 = b << 3;
    int nd = N - d0; if (nd > 8) nd = 8;
    int tid = threadIdx.x;

    if (tid < 8) {
        hist[tid] = 0;
        ads[tid] = (tid < nd) ? a_d[d0 + tid] : 0.f;
    }
    __syncthreads();

    int cnt = gcur[b]; if (cnt > CAP8) cnt = CAP8;
    const unsigned* binp = bins + (size_t)b * CAP8;

    // pass 1: histogram over the 8 local dsts
    for (int c = tid; c < cnt; c += 256) atomicAdd(&hist[binp[c] & 7], 1);
    __syncthreads();
    if (tid == 0) {
        int run = 0;
        for (int i = 0; i < 8; ++i) {
            base[i] = run; cur8[i] = 0;
            run += (hist[i] + 7) & ~7;        // segments padded to x8
        }
    }
    __syncthreads();
    // pass 2: scatter (src, p) into padded segments; exp computed once/edge
    for (int c = tid; c < cnt; c += 256) {
        unsigned pk = binp[c];
        int dl = pk & 7, sv = pk >> 3;
        float ev = a_s[sv] + ads[dl];
        ev = (ev >= 0.f) ? ev : NEG_SLOPE * ev;
        float p = __expf(ev - SHIFT_C);
        int slot = base[dl] + atomicAdd(&cur8[dl], 1);
        int2 sp; sp.x = sv; sp.y = __float_as_int(p);
        spair[slot] = sp;
    }
    // pad sentinels (disjoint slots; concurrent with pass-2 writes)
    if (tid < 64) {
        int dl = tid >> 3, k = tid & 7;
        int n = hist[dl], np = (n + 7) & ~7;
        if (n + k < np) {
            int2 sp; sp.x = d0; sp.y = 0;      // p = 0: no contribution
            spair[base[dl] + n + k] = sp;
        }
    }
    __syncthreads();

    // aggregation: wave w handles dsts dA=d0+w and dB=d0+w+4, interleaved.
    int w = tid >> 6, L = tid & 63;
    float b0 = gat_bias[2 * L] + bias[2 * L];
    float b1 = gat_bias[2 * L + 1] + bias[2 * L + 1];
    float pa = prelu_a[0];

    int dA = d0 + w, dB = d0 + w + 4;
    int dAc = dA < N ? dA : d0, dBc = dB < N ? dB : d0;
    float eA = a_s[dAc] + ads[w];
    eA = (eA >= 0.f) ? eA : NEG_SLOPE * eA;
    float p0A = __expf(eA - SHIFT_C);
    float eB = a_s[dBc] + ads[(w + 4) & 7];
    eB = (eB >= 0.f) ? eB : NEG_SLOPE * eB;
    float p0B = __expf(eB - SHIFT_C);
    short2 hA = *(const short2*)(h16 + (size_t)dAc * OUT_FT + 2 * L);
    short2 hB = *(const short2*)(h16 + (size_t)dBc * OUT_FT + 2 * L);
    float accA0 = p0A * bf2f(hA.x), accA1 = p0A * bf2f(hA.y), dsA = 0.f;
    float accB0 = p0B * bf2f(hB.x), accB1 = p0B * bf2f(hB.y), dsB = 0.f;

    int nA = (hist[w] + 7) & ~7,     begA = base[w];
    int nB = (hist[w + 4] + 7) & ~7, begB = base[w + 4];
    int nmax = nA > nB ? nA : nB;

    for (int c = 0; c < nmax; c += 8) {
        float ppA[8], ppB[8]; short2 hhA[8], hhB[8];
        bool doA = c < nA, doB = c < nB;
        if (doA) {
#pragma unroll
            for (int j = 0; j < 8; ++j) {
                int2 sp = spair[begA + c + j];           // LDS broadcast
                ppA[j] = __int_as_float(sp.y);
                hhA[j] = *(const short2*)(h16 + (size_t)sp.x * OUT_FT + 2 * L);
            }
        }
        if (doB) {
#pragma unroll
            for (int j = 0; j < 8; ++j) {
                int2 sp = spair[begB + c + j];
                ppB[j] = __int_as_float(sp.y);
                hhB[j] = *(const short2*)(h16 + (size_t)sp.x * OUT_FT + 2 * L);
            }
        }
        if (doA) {
#pragma unroll
            for (int j = 0; j < 8; ++j) {
                dsA += ppA[j];
                accA0 += ppA[j] * bf2f(hhA[j].x);
                accA1 += ppA[j] * bf2f(hhA[j].y);
            }
        }
        if (doB) {
#pragma unroll
            for (int j = 0; j < 8; ++j) {
                dsB += ppB[j];
                accB0 += ppB[j] * bf2f(hhB[j].x);
                accB1 += ppB[j] * bf2f(hhB[j].y);
            }
        }
    }
    if (dA < N) {
        float inv = 1.f / (dsA + p0A + 1e-16f);
        float o0 = accA0 * inv + b0;
        float o1 = accA1 * inv + b1;
        o0 = (o0 >= 0.f) ? o0 : pa * o0;
        o1 = (o1 >= 0.f) ? o1 : pa * o1;
        float2 ov; ov.x = o0; ov.y = o1;
        *(float2*)(out + (size_t)dA * OUT_FT + 2 * L) = ov;
    }
    if (dB < N) {
        float inv = 1.f / (dsB + p0B + 1e-16f);
        float o0 = accB0 * inv + b0;
        float o1 = accB1 * inv + b1;
        o0 = (o0 >= 0.f) ? o0 : pa * o0;
        o1 = (o1 >= 0.f) ? o1 : pa * o1;
        float2 ov; ov.x = o0; ov.y = o1;
        *(float2*)(out + (size_t)dB * OUT_FT + 2 * L) = ov;
    }
}

extern "C" void kernel_launch(void* const* d_in, const int* in_sizes, int n_in,
                              void* d_out, int out_size, void* d_ws, size_t ws_size,
                              hipStream_t stream) {
    const float* seq     = (const float*)d_in[0];
    const int*   ei      = (const int*)d_in[1];
    const float* W_fc    = (const float*)d_in[2];
    const float* W_gat   = (const float*)d_in[3];
    const float* att_src = (const float*)d_in[4];
    const float* att_dst = (const float*)d_in[5];
    const float* gat_b   = (const float*)d_in[6];
    const float* bias    = (const float*)d_in[7];
    const float* prelu_a = (const float*)d_in[8];

    int N = in_sizes[0] / IN_FT;
    int E = in_sizes[1] / 2;
    const int* src = ei;
    const int* dst = ei + E;
    int nb = (N + 7) >> 3;            // 1250 bins of 8 dsts

    char* wsb = (char*)d_ws;
    size_t cur = 0;
    auto alloc = [&](size_t bytes) -> void* {
        void* p = (void*)(wsb + cur);
        cur += (bytes + 255) & ~(size_t)255;
        return p;
    };
    short*    h16  = (short*)alloc((size_t)N * OUT_FT * 2);
    float*    a_s  = (float*)alloc((size_t)N * 4);
    float*    a_d  = (float*)alloc((size_t)N * 4);
    int*      gcur = (int*)alloc((size_t)nb * 4);
    unsigned* bins = (unsigned*)alloc((size_t)nb * CAP8 * 4);
    short*    whf  = (short*)alloc((size_t)OUT_FT * IN_FT * 2);

    int GB = (N + 31) / 32;                 // 313 gemm blocks (32 rows each)
    int PB = (E + 2047) / 2048;             // 313 binning blocks

    // K1: combined weight in fragment order + zero bin cursors
    k_prep<<<dim3(256 + (nb + 255) / 256), dim3(256), 0, stream>>>(W_gat, W_fc, whf, gcur, nb);
    // K2: gemm + att logits, co-scheduled with coarse edge binning
    k_main<<<dim3(GB + PB), dim3(256), 0, stream>>>(
        seq, (const short8*)whf, att_src, att_dst, h16, a_s, a_d,
        src, dst, gcur, bins, N, E, nb, GB);
    // K3: per-bin counting sort + interleaved dst-pair register aggregation
    k_agg<<<dim3(nb), dim3(256), 0, stream>>>(
        h16, a_s, a_d, gcur, bins, gat_b, bias, prelu_a, (float*)d_out, N);
}

// Round 3
// 125.071 us; speedup vs baseline: 1.0213x; 1.0048x over previous
//
#include <hip/hip_runtime.h>
#include <hip/hip_bf16.h>

#define IN_FT 512
#define OUT_FT 128
#define NEG_SLOPE 0.2f
#define SHIFT_C 4.0f    // global score shift: softmax-invariant, guards exp overflow
#define CAP8 768        // per-bin capacity: 8 dsts, mean 512 edges, +11 sigma
#define NBMAX 1280

typedef __attribute__((ext_vector_type(8))) short short8;
typedef __attribute__((ext_vector_type(4))) short short4v;
typedef __attribute__((ext_vector_type(4))) float float4v;

__device__ inline short f2bf_s(float x) {
    __hip_bfloat16 b = __float2bfloat16(x);
    union { __hip_bfloat16 b; short s; } u;
    u.b = b;
    return u.s;
}
__device__ inline float bf2f(short s) {
    union { float f; unsigned u; } u;
    u.u = ((unsigned)(unsigned short)s) << 16;
    return u.f;
}

// ---------------- K1: W_comb = W_gat @ W_fc -> bf16 in MFMA B-fragment order
// (blocks 0..255); blocks >=256 zero the bin cursors. ----------------
__global__ void k_prep(const float* __restrict__ Wg,
                       const float* __restrict__ Wf,
                       short* __restrict__ whf,
                       int* __restrict__ gcur, int nb) {
    if (blockIdx.x >= 256) {
        int i = (blockIdx.x - 256) * 256 + threadIdx.x;
        if (i < nb) gcur[i] = 0;
        return;
    }
    int idx = blockIdx.x * blockDim.x + threadIdx.x;  // 0..65535
    int o = idx >> 9;
    int k = idx & 511;
    float s = 0.f;
    // unroll 16: 1 wave/SIMD here, so MLP (outstanding loads) is the only
    // latency hiding — 8 batches of 16 instead of 16 batches of 8.
#pragma unroll 16
    for (int j = 0; j < OUT_FT; ++j)
        s += Wg[o * OUT_FT + j] * Wf[j * IN_FT + k];
    int t = o >> 4, l15 = o & 15;
    int kc = k >> 5, q = (k >> 3) & 3, jj = k & 7;
    whf[(((kc * 8 + t) * 64) + q * 16 + l15) * 8 + jj] = f2bf_s(s);
}

// ---------------- K2: [0..GB) gemm (LDS-staged A, 32 rows/block, NO split-K:
// wave w owns column tiles {2w,2w+1} over full K) + att logits;
// [GB..) phase-1 coarse binning of edges (bin = dst>>3). ----
__launch_bounds__(256)
__global__ void k_main(const float* __restrict__ seq,
                       const short8* __restrict__ whf,
                       const float* __restrict__ att_s_v,
                       const float* __restrict__ att_d_v,
                       short* __restrict__ h16,
                       float* __restrict__ a_s,
                       float* __restrict__ a_d,
                       const int* __restrict__ src,
                       const int* __restrict__ dstv,
                       int* __restrict__ gcur,
                       unsigned* __restrict__ bins,
                       int N, int E, int nb, int GB) {
    __shared__ char smem[33792];   // 32 KB A-tile (2 x 8192 shorts) + 1 KB logit partials
    if (blockIdx.x >= GB) {
        // ---- phase-1 binning: this block owns 2048 consecutive edges ----
        int* hist  = (int*)smem;          // [NBMAX]
        int* sbase = hist + NBMAX;        // [NBMAX]
        int* scur  = sbase + NBMAX;       // 3*1280*4 = 15.4 KB
        int e0 = (blockIdx.x - GB) * 2048;
        for (int t = threadIdx.x; t < nb; t += 256) hist[t] = 0;
        __syncthreads();
        int myd[8];
#pragma unroll
        for (int k = 0; k < 8; ++k) {
            int e = e0 + k * 256 + threadIdx.x;
            myd[k] = (e < E) ? dstv[e] : -1;
            if ((unsigned)myd[k] < (unsigned)N) atomicAdd(&hist[myd[k] >> 3], 1);
            else myd[k] = -1;
        }
        __syncthreads();
        for (int t = threadIdx.x; t < nb; t += 256) {
            int c = hist[t];
            sbase[t] = c ? atomicAdd(&gcur[t], c) : 0;
            scur[t] = 0;
        }
        __syncthreads();
#pragma unroll
        for (int k = 0; k < 8; ++k) {
            if (myd[k] >= 0) {
                int e = e0 + k * 256 + threadIdx.x;
                int b = myd[k] >> 3;
                int slot = sbase[b] + atomicAdd(&scur[b], 1);
                if (slot < CAP8) {
                    int s = src[e];
                    if ((unsigned)s >= (unsigned)N) s = 0;
                    bins[(size_t)b * CAP8 + slot] = ((unsigned)s << 3) | (myd[k] & 7);
                }
            }
        }
        return;
    }
    // ---- gemm: tile 32 rows x 128 cols. Wave w owns col tiles {2w,2w+1};
    //      loops full K (16 kc steps), accumulating 4 fragments — no split-K
    //      reduction, no idle-wave epilogue. ----
    short* As = (short*)smem;              // [rg][kc][q][r16][8] shorts; rg stride 8192 SHORTS

    int wave = threadIdx.x >> 6;
    int lane = threadIdx.x & 63;
    int l15 = lane & 15, quad = lane >> 4;
    int rows0 = blockIdx.x * 32;

#pragma unroll
    for (int i = 0; i < 16; ++i) {
        int idx = threadIdx.x + 256 * i;   // 0..4095 float4s
        int r = idx >> 7, c4 = idx & 127;  // r 0..31
        int row = rows0 + r;
        int rowc = row < N ? row : N - 1;
        float4 v = *(const float4*)(seq + (size_t)rowc * IN_FT + c4 * 4);
        short4v b;
        b[0] = f2bf_s(v.x); b[1] = f2bf_s(v.y); b[2] = f2bf_s(v.z); b[3] = f2bf_s(v.w);
        int rg = r >> 4, r16 = r & 15;
        int kc = c4 >> 3, q = (c4 >> 1) & 3, half = c4 & 1;
        *(short4v*)(As + rg * 8192 + ((kc * 4 + q) * 16 + r16) * 8 + half * 4) = b;
    }
    __syncthreads();

    float4v accs[2][2];
#pragma unroll
    for (int rg = 0; rg < 2; ++rg)
#pragma unroll
        for (int tt = 0; tt < 2; ++tt) accs[rg][tt] = (float4v){0.f, 0.f, 0.f, 0.f};

    const short8* wp = whf + lane;
#pragma unroll
    for (int kc = 0; kc < 16; ++kc) {
        short8 a0 = *(const short8*)(As + ((kc * 4 + quad) * 16 + l15) * 8);
        short8 a1 = *(const short8*)(As + 8192 + ((kc * 4 + quad) * 16 + l15) * 8);
        short8 b0 = wp[(size_t)(kc * 8 + 2 * wave) * 64];
        short8 b1 = wp[(size_t)(kc * 8 + 2 * wave + 1) * 64];
        accs[0][0] = __builtin_amdgcn_mfma_f32_16x16x32_bf16(a0, b0, accs[0][0], 0, 0, 0);
        accs[0][1] = __builtin_amdgcn_mfma_f32_16x16x32_bf16(a0, b1, accs[0][1], 0, 0, 0);
        accs[1][0] = __builtin_amdgcn_mfma_f32_16x16x32_bf16(a1, b0, accs[1][0], 0, 0, 0);
        accs[1][1] = __builtin_amdgcn_mfma_f32_16x16x32_bf16(a1, b1, accs[1][1], 0, 0, 0);
    }

    // epilogue (all 4 waves): h16 stores for this wave's 2 column tiles
#pragma unroll
    for (int rg = 0; rg < 2; ++rg)
#pragma unroll
        for (int tt = 0; tt < 2; ++tt) {
            int t = 2 * wave + tt;
#pragma unroll
            for (int r = 0; r < 4; ++r) {
                int rr = rows0 + rg * 16 + quad * 4 + r;
                if (rr < N)
                    h16[(size_t)rr * OUT_FT + t * 16 + l15] = f2bf_s(accs[rg][tt][r]);
            }
        }

    // logits: per-wave partial dot over its 32 features, then cross-wave sum
    float asv0 = att_s_v[(2 * wave) * 16 + l15];
    float asv1 = att_s_v[(2 * wave + 1) * 16 + l15];
    float adv0 = att_d_v[(2 * wave) * 16 + l15];
    float adv1 = att_d_v[(2 * wave + 1) * 16 + l15];
    float* psh = (float*)(smem + 32768);   // [4][32]
    float* pdh = psh + 128;                // [4][32]
#pragma unroll
    for (int rg = 0; rg < 2; ++rg)
#pragma unroll
        for (int r = 0; r < 4; ++r) {
            float ps = accs[rg][0][r] * asv0 + accs[rg][1][r] * asv1;
            float pd = accs[rg][0][r] * adv0 + accs[rg][1][r] * adv1;
#pragma unroll
            for (int m = 1; m < 16; m <<= 1) {
                ps += __shfl_xor(ps, m);
                pd += __shfl_xor(pd, m);
            }
            if (l15 == 0) {
                int row = rg * 16 + quad * 4 + r;
                psh[wave * 32 + row] = ps;
                pdh[wave * 32 + row] = pd;
            }
        }
    __syncthreads();
    if (threadIdx.x < 32) {
        int rr = rows0 + threadIdx.x;
        if (rr < N) {
            float s = psh[threadIdx.x] + psh[32 + threadIdx.x] +
                      psh[64 + threadIdx.x] + psh[96 + threadIdx.x];
            float d = pdh[threadIdx.x] + pdh[32 + threadIdx.x] +
                      pdh[64 + threadIdx.x] + pdh[96 + threadIdx.x];
            a_s[rr] = s; a_d[rr] = d;
        }
    }
}

// ---------------- K3: one block per bin (8 dsts). In-LDS counting sort into
// 8-padded (src, p) segments (sentinels p=0), then HALF-WAVE-per-dst register
// accumulation: lane covers 4 features (short4 loads); wave processes 2 edges
// per step with 1 LDS read + 1 dwordx2 gather. ----
__launch_bounds__(256)
__global__ void k_agg(const short* __restrict__ h16, const float* __restrict__ a_s,
                      const float* __restrict__ a_d,
                      const int* __restrict__ gcur, const unsigned* __restrict__ bins,
                      const float* __restrict__ gat_bias,
                      const float* __restrict__ bias,
                      const float* __restrict__ prelu_a,
                      float* __restrict__ out, int N) {
    __shared__ int2  spair[CAP8 + 64];
    __shared__ int   hist[8], base[8], cur8[8];
    __shared__ float ads[8];
    int b = blockIdx.x;
    int d0 = b << 3;
    int nd = N - d0; if (nd > 8) nd = 8;
    int tid = threadIdx.x;

    if (tid < 8) {
        hist[tid] = 0;
        ads[tid] = (tid < nd) ? a_d[d0 + tid] : 0.f;
    }
    __syncthreads();

    int cnt = gcur[b]; if (cnt > CAP8) cnt = CAP8;
    const unsigned* binp = bins + (size_t)b * CAP8;

    // pass 1: histogram over the 8 local dsts
    for (int c = tid; c < cnt; c += 256) atomicAdd(&hist[binp[c] & 7], 1);
    __syncthreads();
    if (tid == 0) {
        int run = 0;
        for (int i = 0; i < 8; ++i) {
            base[i] = run; cur8[i] = 0;
            run += (hist[i] + 7) & ~7;        // segments padded to x8
        }
    }
    __syncthreads();
    // pass 2: scatter (src, p) into padded segments; exp computed once/edge
    for (int c = tid; c < cnt; c += 256) {
        unsigned pk = binp[c];
        int dl = pk & 7, sv = pk >> 3;
        float ev = a_s[sv] + ads[dl];
        ev = (ev >= 0.f) ? ev : NEG_SLOPE * ev;
        float p = __expf(ev - SHIFT_C);
        int slot = base[dl] + atomicAdd(&cur8[dl], 1);
        int2 sp; sp.x = sv; sp.y = __float_as_int(p);
        spair[slot] = sp;
    }
    // pad sentinels (disjoint slots; concurrent with pass-2 writes)
    if (tid < 64) {
        int dl = tid >> 3, k = tid & 7;
        int n = hist[dl], np = (n + 7) & ~7;
        if (n + k < np) {
            int2 sp; sp.x = d0; sp.y = 0;      // p = 0: no contribution
            spair[base[dl] + n + k] = sp;
        }
    }
    __syncthreads();

    // aggregation: wave w, half 0 -> dst d0+w, half 1 -> dst d0+w+4.
    // Each lane owns 4 consecutive features (short4 = 8 B gathers).
    int w = tid >> 6, lane = tid & 63;
    int half = lane >> 5, l32 = lane & 31;
    int dl = w + half * 4;
    int d = d0 + dl;
    int dc = d < N ? d : d0;

    float4 gb  = *(const float4*)(gat_bias + 4 * l32);
    float4 bb4 = *(const float4*)(bias + 4 * l32);
    float pa = prelu_a[0];

    // self-loop contribution
    float es = a_s[dc] + ads[dl];
    es = (es >= 0.f) ? es : NEG_SLOPE * es;
    float p0 = __expf(es - SHIFT_C);
    short4v hs = *(const short4v*)(h16 + (size_t)dc * OUT_FT + 4 * l32);
    float acc0 = p0 * bf2f(hs[0]), acc1 = p0 * bf2f(hs[1]);
    float acc2 = p0 * bf2f(hs[2]), acc3 = p0 * bf2f(hs[3]);
    float ds = 0.f;

    int np  = (hist[dl] + 7) & ~7;
    int beg = base[dl];
    int npo = __shfl_xor(np, 32);          // other half's padded count
    int nmax = np > npo ? np : npo;

    for (int c = 0; c < nmax; c += 8) {
        // batch-uniform per half (np is x8): clamp exhausted half to slot 0, p=0
        bool ok = c < np;
        int bb = ok ? (beg + c) : 0;
        float pp[8]; short4v hh[8];
#pragma unroll
        for (int j = 0; j < 8; ++j) {
            int2 sp = spair[bb + j];               // broadcast within half
            pp[j] = ok ? __int_as_float(sp.y) : 0.f;
            hh[j] = *(const short4v*)(h16 + (size_t)sp.x * OUT_FT + 4 * l32);
        }
#pragma unroll
        for (int j = 0; j < 8; ++j) {
            ds   += pp[j];
            acc0 += pp[j] * bf2f(hh[j][0]);
            acc1 += pp[j] * bf2f(hh[j][1]);
            acc2 += pp[j] * bf2f(hh[j][2]);
            acc3 += pp[j] * bf2f(hh[j][3]);
        }
    }
    if (d < N) {
        float inv = 1.f / (ds + p0 + 1e-16f);
        float o0 = acc0 * inv + gb.x + bb4.x;
        float o1 = acc1 * inv + gb.y + bb4.y;
        float o2 = acc2 * inv + gb.z + bb4.z;
        float o3 = acc3 * inv + gb.w + bb4.w;
        o0 = (o0 >= 0.f) ? o0 : pa * o0;
        o1 = (o1 >= 0.f) ? o1 : pa * o1;
        o2 = (o2 >= 0.f) ? o2 : pa * o2;
        o3 = (o3 >= 0.f) ? o3 : pa * o3;
        float4 ov; ov.x = o0; ov.y = o1; ov.z = o2; ov.w = o3;
        *(float4*)(out + (size_t)d * OUT_FT + 4 * l32) = ov;
    }
}

extern "C" void kernel_launch(void* const* d_in, const int* in_sizes, int n_in,
                              void* d_out, int out_size, void* d_ws, size_t ws_size,
                              hipStream_t stream) {
    const float* seq     = (const float*)d_in[0];
    const int*   ei      = (const int*)d_in[1];
    const float* W_fc    = (const float*)d_in[2];
    const float* W_gat   = (const float*)d_in[3];
    const float* att_src = (const float*)d_in[4];
    const float* att_dst = (const float*)d_in[5];
    const float* gat_b   = (const float*)d_in[6];
    const float* bias    = (const float*)d_in[7];
    const float* prelu_a = (const float*)d_in[8];

    int N = in_sizes[0] / IN_FT;
    int E = in_sizes[1] / 2;
    const int* src = ei;
    const int* dst = ei + E;
    int nb = (N + 7) >> 3;            // 1250 bins of 8 dsts

    char* wsb = (char*)d_ws;
    size_t cur = 0;
    auto alloc = [&](size_t bytes) -> void* {
        void* p = (void*)(wsb + cur);
        cur += (bytes + 255) & ~(size_t)255;
        return p;
    };
    short*    h16  = (short*)alloc((size_t)N * OUT_FT * 2);
    float*    a_s  = (float*)alloc((size_t)N * 4);
    float*    a_d  = (float*)alloc((size_t)N * 4);
    int*      gcur = (int*)alloc((size_t)nb * 4);
    unsigned* bins = (unsigned*)alloc((size_t)nb * CAP8 * 4);
    short*    whf  = (short*)alloc((size_t)OUT_FT * IN_FT * 2);

    int GB = (N + 31) / 32;                 // 313 gemm blocks (32 rows each)
    int PB = (E + 2047) / 2048;             // 313 binning blocks

    // K1: combined weight in fragment order + zero bin cursors
    k_prep<<<dim3(256 + (nb + 255) / 256), dim3(256), 0, stream>>>(W_gat, W_fc, whf, gcur, nb);
    // K2: gemm + att logits, co-scheduled with coarse edge binning
    k_main<<<dim3(GB + PB), dim3(256), 0, stream>>>(
        seq, (const short8*)whf, att_src, att_dst, h16, a_s, a_d,
        src, dst, gcur, bins, N, E, nb, GB);
    // K3: per-bin counting sort + half-wave-per-dst register aggregation
    k_agg<<<dim3(nb), dim3(256), 0, stream>>>(
        h16, a_s, a_d, gcur, bins, gat_b, bias, prelu_a, (float*)d_out, N);
}